// Round 3
// baseline (185.997 us; speedup 1.0000x reference)
//
#include <hip/hip_runtime.h>

// NormEMAVectorQuantizer on MI355X (gfx950)
// N=8192 tokens, C=32, K=8192 codes, B=32, H*W=256.
// R20 = R19 with the launch bug fixed: k_rescan is one WAVE per token
// (n = blockIdx.x*4 + wave) and must be launched with NTOK/4 = 2048 blocks;
// R19 launched 32 blocks -> tokens 128..8191 never written (absmax 5472 on
// ids). Algorithm unchanged:
//  k_prep / k_max / k_final: R17's proven base (byte-identical).
//  k_rescan: per token, reduce the 32 chunk maxima from pmax -> gmax, pick
//  chunks with pmax >= gmax - eps (~1.5-2/token), fp32-rescore ALL 256 codes
//  of each passing chunk (4 codes/lane), wave-reduce a packed (score,
//  lowest-code) key, plain-store packed[n] (no atomics, no zero-init).
// Certificate (same as R17): bf16 dot err: 2*err <= 0.0078 < eps=0.01 for
// unit rows. Any code c whose fp32 score ties the max has bf16 score
// >= gmax_bf16 - 2*err > gmax_bf16 - eps, so its chunk's pmax passes the
// threshold and c is exact-rescored in fp32; key = (fmap(s)<<13)|(8191-code)
// reproduces numpy lowest-index tie-break.
// R18 post-mortem encoded here: harvest-in-sweep pushed VGPR 128->164
// (4->3 blocks/CU on a latency-bound kernel) and harvested ~32 cands/token
// (per-chunk threshold: each chunk's own max always passes) -> 76us. Sparse
// work lives in its own tiny kernel; the sweep stays branch-free.
//
// Outputs (float32, concatenated):
//   [0 .. 262144)        z_q_out [B,C,H,W]
//   [262144]             loss (scalar)
//   [262145 .. 270337)   token_ids [B,H,W] as float
//   [270337 .. 532481)   new_embedding [K,C]
//   [532481 .. 540673)   new_cluster_sizes [K]

#define NTOK   8192
#define NCODE  8192
#define CDIM   32
#define HW     256
#define DECAYF 0.99f
#define EPSF   0.01f

#define OUT_ZQ   0
#define OUT_LOSS 262144
#define OUT_IDS  262145
#define OUT_EMB  270337
#define OUT_CS   532481

// workspace byte offsets
#define WS_ZN     0u        // f32 [N,C]                = 1048576
#define WS_ZNBF   1048576u  // bf16 [N,C]               = 524288
#define WS_EBF    1572864u  // bf16 [K,C]               = 524288
#define WS_PMAX   2097152u  // f32 [32][N]              = 1048576
#define WS_PACK   3145728u  // u64 [N]                  = 65536   (end 3211264)

#define CHUNK  256
#define NCHUNK (NCODE / CHUNK)  // 32
#define TILES  (CHUNK / 16)     // 16

typedef __attribute__((ext_vector_type(8))) short bf16x8;
typedef __attribute__((ext_vector_type(4))) float f32x4;

__device__ inline unsigned short f2bf(float x) {
    unsigned u = __float_as_uint(x);
    return (unsigned short)((u + 0x7FFFu + ((u >> 16) & 1u)) >> 16);
}
__device__ inline unsigned fmap(float s) {   // monotonic f32 -> u32
    unsigned u = __float_as_uint(s);
    return (u & 0x80000000u) ? ~u : (u | 0x80000000u);
}

// stage one 256x32 bf16 chunk into LDS with rows padded to 5 float4 units
// (80B): banks cycle 20*row%32 -> max 2-way conflict on read and write.
__device__ inline void stage_chunk(const unsigned short* __restrict__ ebf,
                                   int kbase, float4* lbs5, int t) {
    const float4* src = (const float4*)(ebf + (size_t)kbase * CDIM);
#pragma unroll
    for (int j = 0; j < 4; ++j) {
        int u = t + j * 256;                      // global float4 unit in chunk
        int row = u >> 2, seg = u & 3;
        lbs5[row * 5 + seg] = src[u];
    }
}

// exact fp32 dot, arithmetic identical to R17's proven rescore
__device__ __forceinline__ float dot32(const float* zr, const float* __restrict__ emb,
                                       int code) {
    const float4* ep4 = (const float4*)(emb + (size_t)code * CDIM);
    float a0 = 0.f, a1 = 0.f, a2 = 0.f, a3 = 0.f;
#pragma unroll
    for (int j = 0; j < 8; ++j) {
        float4 e4 = ep4[j];
        a0 = __builtin_fmaf(zr[4 * j + 0], e4.x, a0);
        a1 = __builtin_fmaf(zr[4 * j + 1], e4.y, a1);
        a2 = __builtin_fmaf(zr[4 * j + 2], e4.z, a2);
        a3 = __builtin_fmaf(zr[4 * j + 3], e4.w, a3);
    }
    return (a0 + a1) + (a2 + a3);
}

// -------- Kernel A: prep (norm + bf16 + emb bf16) + zero loss ------------------
__global__ __launch_bounds__(256) void k_prep(const float* __restrict__ z,
                                              const float* __restrict__ emb,
                                              float* __restrict__ zn,
                                              unsigned short* __restrict__ znbf,
                                              unsigned short* __restrict__ ebf,
                                              float* __restrict__ out) {
    int bid = blockIdx.x, t = threadIdx.x;
    if (bid < 32) {                               // token norm -> zn, znbf
        int n = bid * 256 + t;
        int b = n >> 8, hw = n & 255;
        const float* zp = z + (size_t)b * (CDIM * HW) + hw;
        float v[CDIM];
        float ss = 0.f;
#pragma unroll
        for (int c = 0; c < CDIM; ++c) {
            float tv = zp[c * HW];                // coalesced per c
            v[c] = tv;
            ss += tv * tv;
        }
        float d = fmaxf(sqrtf(ss), 1e-12f);
        float* o = zn + (size_t)n * CDIM;
        unsigned short* ob = znbf + (size_t)n * CDIM;
#pragma unroll
        for (int c = 0; c < CDIM; ++c) {
            float tv = v[c] / d;
            o[c] = tv;
            ob[c] = f2bf(tv);
        }
    } else if (bid < 160) {                       // emb -> ebf
        int base = (bid - 32) * 2048 + t * 8;
        const float4* s = (const float4*)(emb + base);
        float4 x4 = s[0], y4 = s[1];
        ushort4 u0 = {f2bf(x4.x), f2bf(x4.y), f2bf(x4.z), f2bf(x4.w)};
        ushort4 u1 = {f2bf(y4.x), f2bf(y4.y), f2bf(y4.z), f2bf(y4.w)};
        *(ushort4*)(ebf + base) = u0;
        *(ushort4*)(ebf + base + 4) = u1;
    } else {                                      // bid==160: zero loss slot
        if (t == 0) out[OUT_LOSS] = 0.f;
    }
}

// -------- Kernel B: MFMA sweep -> pmax[chunk][tok] (R17-identical) -------------
__global__ __launch_bounds__(256) void k_max(const unsigned short* __restrict__ znbf,
                                             const unsigned short* __restrict__ ebf,
                                             float* __restrict__ pmax) {
    __shared__ float4 lbs5[CHUNK * 5];            // 20 KiB, 80B rows
    __shared__ float lmax[256];
    int kbase = blockIdx.y * CHUNK;
    stage_chunk(ebf, kbase, lbs5, threadIdx.x);
    __syncthreads();

    int wave = threadIdx.x >> 6, lane = threadIdx.x & 63;
    int col = lane & 15, quad = lane >> 4;
    int wtok = blockIdx.x * 256 + wave * 64;

    bf16x8 a[4];                                  // 4 frags = 64 tokens
#pragma unroll
    for (int f = 0; f < 4; ++f)
        a[f] = *(const bf16x8*)(znbf + (size_t)(wtok + f * 16 + col) * CDIM + quad * 8);

    const bf16x8* bl = (const bf16x8*)lbs5;       // 16B units, row stride 5
    const f32x4 zero4 = {0.f, 0.f, 0.f, 0.f};
    float m[4][4];
#pragma unroll
    for (int f = 0; f < 4; ++f)
#pragma unroll
        for (int r = 0; r < 4; ++r) m[f][r] = -1e30f;

    for (int t = 0; t < TILES; ++t) {
        bf16x8 b = bl[(t * 16 + col) * 5 + quad];
#pragma unroll
        for (int f = 0; f < 4; ++f) {
            f32x4 d = __builtin_amdgcn_mfma_f32_16x16x32_bf16(a[f], b, zero4, 0, 0, 0);
#pragma unroll
            for (int r = 0; r < 4; ++r) m[f][r] = fmaxf(m[f][r], d[r]);
        }
    }
#pragma unroll
    for (int f = 0; f < 4; ++f)
#pragma unroll
        for (int r = 0; r < 4; ++r) {
            float v = m[f][r];
#pragma unroll
            for (int s = 1; s < 16; s <<= 1) v = fmaxf(v, __shfl_xor(v, s));
            if (col == 0) lmax[wave * 64 + f * 16 + quad * 4 + r] = v;
        }
    __syncthreads();
    pmax[(size_t)blockIdx.y * NTOK + blockIdx.x * 256 + threadIdx.x] = lmax[threadIdx.x];
}

// -------- Kernel C: per-token sparse fp32 rescan of passing chunks -------------
// One wave per token (grid = NTOK/4 blocks of 4 waves). ~1.5-2 chunks pass
// per token; each passing chunk is fully fp32-rescored (256 codes, 4/lane)
// from the fp32 emb (L2-resident).
__global__ __launch_bounds__(256) void k_rescan(const float* __restrict__ zn,
                                                const float* __restrict__ emb,
                                                const float* __restrict__ pmax,
                                                unsigned long long* __restrict__ packed) {
    int wave = threadIdx.x >> 6, lane = threadIdx.x & 63;
    int n = blockIdx.x * 4 + wave;

    // chunk maxima: lanes 0..31 hold pmax[lane][n]
    float pm = -1e30f;
    if (lane < 32) pm = pmax[(size_t)lane * NTOK + n];
    float mx = pm;
#pragma unroll
    for (int s = 1; s < 64; s <<= 1) mx = fmaxf(mx, __shfl_xor(mx, s));
    float thr = mx - EPSF;
    unsigned m32 = (unsigned)(__ballot(pm >= thr) & 0xFFFFFFFFull);

    // token row (broadcast same-address loads across the wave)
    float zr[CDIM];
    const float4* zp4 = (const float4*)(zn + (size_t)n * CDIM);
#pragma unroll
    for (int j = 0; j < 8; ++j) {
        float4 v4 = zp4[j];
        zr[4 * j + 0] = v4.x;
        zr[4 * j + 1] = v4.y;
        zr[4 * j + 2] = v4.z;
        zr[4 * j + 3] = v4.w;
    }

    unsigned long long kbest = 0ull;
    while (m32) {
        int ch = __ffs(m32) - 1;
        m32 &= m32 - 1;
#pragma unroll
        for (int j = 0; j < 4; ++j) {
            int code = ch * CHUNK + j * 64 + lane;
            float s = dot32(zr, emb, code);
            unsigned long long key = ((unsigned long long)fmap(s) << 13) |
                                     (unsigned long long)(8191 - code);
            kbest = kbest > key ? kbest : key;
        }
    }
#pragma unroll
    for (int s = 1; s < 64; s <<= 1) {
        unsigned long long o = __shfl_xor(kbest, s);
        kbest = kbest > o ? kbest : o;
    }
    if (lane == 0) packed[n] = kbest;             // one wave per token: plain store
}

// -------- Kernel D: fused epilogue, 256 blocks (R17-identical) -----------------
// Block b: (a) ids/z_q/loss for tokens 32b..32b+31; (b) bins+esum for codes
// 32b..32b+31 by scanning all packed (coalesced, ~8 hits/wave), then EMA.
__global__ __launch_bounds__(256) void k_final(const unsigned long long* __restrict__ packed,
                                               const float* __restrict__ zn,
                                               const float* __restrict__ emb,
                                               const float* __restrict__ cs,
                                               float* __restrict__ out) {
    __shared__ float lesum[32][32];               // 4 KiB
    __shared__ int lbins[32];
    __shared__ int lsid[32];
    __shared__ float ls4[4];

    int blk = blockIdx.x, t = threadIdx.x;
    int wave = t >> 6, lane = t & 63;
    int tok0 = blk * 32, kbase = blk * 32;

    if (t < 32) lbins[t] = 0;
#pragma unroll
    for (int i = 0; i < 4; ++i) {
        int idx = i * 256 + t;
        lesum[idx >> 5][idx & 31] = 0.f;
    }
    if (t < 32) {                                 // unpack ids for our tokens
        int n = tok0 + t;
        int id = 8191 - (int)(packed[n] & 8191ull);
        lsid[t] = id;
        out[OUT_IDS + n] = (float)id;
    }
    __syncthreads();

    // ---- z_q gather + transpose-out + loss partial ----
    float s = 0.f;
#pragma unroll
    for (int i = 0; i < 4; ++i) {
        int idx = i * 256 + t;
        int tl = idx >> 5, c = idx & 31;
        int n = tok0 + tl;
        int id = lsid[tl];
        float ev = emb[(size_t)id * CDIM + c];    // <=32 rows, L1/L2
        float zv = zn[(size_t)n * CDIM + c];      // coalesced row reads
        int b = n >> 8, hw = n & 255;
        out[OUT_ZQ + ((size_t)b * CDIM + c) * HW + hw] = ev;
        float dd = ev - zv;
        s += dd * dd;
    }
#pragma unroll
    for (int off = 32; off > 0; off >>= 1) s += __shfl_down(s, off);
    if (lane == 0) ls4[wave] = s;
    __syncthreads();
    if (t == 0)
        atomicAdd(out + OUT_LOSS,
                  (ls4[0] + ls4[1] + ls4[2] + ls4[3]) * (1.0f / 262144.0f));

    // ---- bins + esum: scan all tokens for hits in our code window ----
    for (int i = 0; i < 32; ++i) {
        int n = i * 256 + t;                      // coalesced
        int id = 8191 - (int)(packed[n] & 8191ull);
        unsigned kl = (unsigned)(id - kbase);
        if (kl < 32u) {                           // ~8 hits per wave total
            atomicAdd(&lbins[kl], 1);
            const float* zp = zn + (size_t)n * CDIM;
#pragma unroll
            for (int c = 0; c < CDIM; ++c)
                atomicAdd(&lesum[kl][c], zp[c]);
        }
    }
    __syncthreads();

    // ---- EMA update + renormalize for our 32 codes ----
#pragma unroll
    for (int i = 0; i < 4; ++i) {
        int idx = i * 256 + t;
        int kl = idx >> 5, c = idx & 31;
        int k = kbase + kl;
        int bi = lbins[kl];
        float bf = (float)bi;
        bool zero = (bi == 0);
        float tv = lesum[kl][c] / (zero ? 1.0f : bf);
        float ss = tv * tv;
#pragma unroll
        for (int sh = 1; sh < 32; sh <<= 1) ss += __shfl_xor(ss, sh);
        float d = fmaxf(sqrtf(ss), 1e-12f);
        float ew = emb[(size_t)k * CDIM + c];
        float en = zero ? ew : (tv / d);
        float w = ew * DECAYF + (1.0f - DECAYF) * en;
        float ss2 = w * w;
#pragma unroll
        for (int sh = 1; sh < 32; sh <<= 1) ss2 += __shfl_xor(ss2, sh);
        float d2 = fmaxf(sqrtf(ss2), 1e-12f);
        out[OUT_EMB + (size_t)k * CDIM + c] = w / d2;
        if (c == 0) out[OUT_CS + k] = cs[k] * DECAYF + (1.0f - DECAYF) * bf;
    }
}

extern "C" void kernel_launch(void* const* d_in, const int* in_sizes, int n_in,
                              void* d_out, int out_size, void* d_ws, size_t ws_size,
                              hipStream_t stream) {
    const float* z   = (const float*)d_in[0];   // [32,32,16,16]
    const float* emb = (const float*)d_in[1];   // [8192,32]
    const float* cs  = (const float*)d_in[2];   // [8192]
    float* out = (float*)d_out;
    char* ws = (char*)d_ws;

    float* zn                  = (float*)(ws + WS_ZN);
    unsigned short* znbf       = (unsigned short*)(ws + WS_ZNBF);
    unsigned short* ebf        = (unsigned short*)(ws + WS_EBF);
    float* pmax                = (float*)(ws + WS_PMAX);
    unsigned long long* packed = (unsigned long long*)(ws + WS_PACK);

    k_prep<<<dim3(161), 256, 0, stream>>>(z, emb, zn, znbf, ebf, out);
    k_max<<<dim3(NTOK / 256, NCHUNK), 256, 0, stream>>>(znbf, ebf, pmax);
    k_rescan<<<dim3(NTOK / 4), 256, 0, stream>>>(zn, emb, pmax, packed);
    k_final<<<dim3(256), 256, 0, stream>>>(packed, zn, emb, cs, out);
}

// Round 4
// 142.984 us; speedup vs baseline: 1.3008x; 1.3008x over previous
//
#include <hip/hip_runtime.h>

// NormEMAVectorQuantizer on MI355X (gfx950)
// N=8192 tokens, C=32, K=8192 codes, B=32, H*W=256.
// R21 = R20 with k_rescan's memory layout fixed (R20 post-mortem: per-lane
// row gather -> 64 cache lines per load instruction -> L1 line-throughput
// bound, 90us at 6.7% VALUBusy / 1.2% HBM):
//  (a) k_prep additionally writes embT [C][K] f32 (LDS-tile transpose, 1MB,
//      one-time). k_rescan's fp32 rescore is c-major: per c, lanes load
//      embT[c][ch*256+4*lane] float4 = 1KB contiguous per instruction.
//      Accumulation grouped acc[c&3][j], finalized (a0+a1)+(a2+a3) ->
//      bit-identical fp32 order to the proven dot32 (ids exactness kept).
//  (b) k_max stores pmaxT[token][chunk] (scattered 4B stores, fire-and-
//      forget) so k_rescan reads its 32 chunk maxima as ONE 128B line.
// Algorithm/certificate unchanged (R17): bf16 dot err 2*err <= 0.0078 <
// eps=0.01 for unit rows; any fp32-argmax-tying code's chunk passes
// pmax >= gmax-eps and is exact-rescored in fp32; key =
// (fmap(s)<<13)|(8191-code) reproduces numpy lowest-index tie-break.
// One wave per token in k_rescan (grid NTOK/4, 4 waves/block) -> plain store.
//
// Outputs (float32, concatenated):
//   [0 .. 262144)        z_q_out [B,C,H,W]
//   [262144]             loss (scalar)
//   [262145 .. 270337)   token_ids [B,H,W] as float
//   [270337 .. 532481)   new_embedding [K,C]
//   [532481 .. 540673)   new_cluster_sizes [K]

#define NTOK   8192
#define NCODE  8192
#define CDIM   32
#define HW     256
#define DECAYF 0.99f
#define EPSF   0.01f

#define OUT_ZQ   0
#define OUT_LOSS 262144
#define OUT_IDS  262145
#define OUT_EMB  270337
#define OUT_CS   532481

// workspace byte offsets
#define WS_ZN     0u        // f32 [N,C]                = 1048576
#define WS_ZNBF   1048576u  // bf16 [N,C]               = 524288
#define WS_EBF    1572864u  // bf16 [K,C]               = 524288
#define WS_PMAX   2097152u  // f32 [N][32] (pmaxT)      = 1048576
#define WS_PACK   3145728u  // u64 [N]                  = 65536
#define WS_EMBT   3211264u  // f32 [C][K] (embT)        = 1048576 (end 4259840)

#define CHUNK  256
#define NCHUNK (NCODE / CHUNK)  // 32
#define TILES  (CHUNK / 16)     // 16

typedef __attribute__((ext_vector_type(8))) short bf16x8;
typedef __attribute__((ext_vector_type(4))) float f32x4;

__device__ inline unsigned short f2bf(float x) {
    unsigned u = __float_as_uint(x);
    return (unsigned short)((u + 0x7FFFu + ((u >> 16) & 1u)) >> 16);
}
__device__ inline unsigned fmap(float s) {   // monotonic f32 -> u32
    unsigned u = __float_as_uint(s);
    return (u & 0x80000000u) ? ~u : (u | 0x80000000u);
}

// stage one 256x32 bf16 chunk into LDS with rows padded to 5 float4 units
// (80B): banks cycle 20*row%32 -> max 2-way conflict on read and write.
__device__ inline void stage_chunk(const unsigned short* __restrict__ ebf,
                                   int kbase, float4* lbs5, int t) {
    const float4* src = (const float4*)(ebf + (size_t)kbase * CDIM);
#pragma unroll
    for (int j = 0; j < 4; ++j) {
        int u = t + j * 256;                      // global float4 unit in chunk
        int row = u >> 2, seg = u & 3;
        lbs5[row * 5 + seg] = src[u];
    }
}

// -------- Kernel A: prep (norm + bf16 + emb bf16 + embT transpose) -------------
__global__ __launch_bounds__(256) void k_prep(const float* __restrict__ z,
                                              const float* __restrict__ emb,
                                              float* __restrict__ zn,
                                              unsigned short* __restrict__ znbf,
                                              unsigned short* __restrict__ ebf,
                                              float* __restrict__ embT,
                                              float* __restrict__ out) {
    __shared__ float tile[32][65];                // transpose tile (emb branch)
    int bid = blockIdx.x, t = threadIdx.x;
    if (bid < 32) {                               // token norm -> zn, znbf
        int n = bid * 256 + t;
        int b = n >> 8, hw = n & 255;
        const float* zp = z + (size_t)b * (CDIM * HW) + hw;
        float v[CDIM];
        float ss = 0.f;
#pragma unroll
        for (int c = 0; c < CDIM; ++c) {
            float tv = zp[c * HW];                // coalesced per c
            v[c] = tv;
            ss += tv * tv;
        }
        float d = fmaxf(sqrtf(ss), 1e-12f);
        float* o = zn + (size_t)n * CDIM;
        unsigned short* ob = znbf + (size_t)n * CDIM;
#pragma unroll
        for (int c = 0; c < CDIM; ++c) {
            float tv = v[c] / d;
            o[c] = tv;
            ob[c] = f2bf(tv);
        }
    } else if (bid < 160) {                       // emb -> ebf + embT
        int blk = bid - 32;
        int r0 = blk * 64;                        // 64 code rows per block
        int base = blk * 2048 + t * 8;
        const float4* s = (const float4*)(emb + base);
        float4 x4 = s[0], y4 = s[1];
        ushort4 u0 = {f2bf(x4.x), f2bf(x4.y), f2bf(x4.z), f2bf(x4.w)};
        ushort4 u1 = {f2bf(y4.x), f2bf(y4.y), f2bf(y4.z), f2bf(y4.w)};
        *(ushort4*)(ebf + base) = u0;
        *(ushort4*)(ebf + base + 4) = u1;
        // transpose: thread t holds row lr=t>>2, cols (t&3)*8 .. +7
        int lr = t >> 2, c0 = (t & 3) * 8;
        tile[c0 + 0][lr] = x4.x; tile[c0 + 1][lr] = x4.y;
        tile[c0 + 2][lr] = x4.z; tile[c0 + 3][lr] = x4.w;
        tile[c0 + 4][lr] = y4.x; tile[c0 + 5][lr] = y4.y;
        tile[c0 + 6][lr] = y4.z; tile[c0 + 7][lr] = y4.w;
        __syncthreads();
        int c = t >> 3, seg = t & 7;              // 8 threads per c-row
        float4 w0 = {tile[c][seg * 8 + 0], tile[c][seg * 8 + 1],
                     tile[c][seg * 8 + 2], tile[c][seg * 8 + 3]};
        float4 w1 = {tile[c][seg * 8 + 4], tile[c][seg * 8 + 5],
                     tile[c][seg * 8 + 6], tile[c][seg * 8 + 7]};
        float* dst = embT + (size_t)c * NCODE + r0 + seg * 8;
        *(float4*)dst = w0;
        *(float4*)(dst + 4) = w1;
    } else {                                      // bid==160: zero loss slot
        if (t == 0) out[OUT_LOSS] = 0.f;
    }
}

// -------- Kernel B: MFMA sweep -> pmaxT[tok][chunk] ----------------------------
__global__ __launch_bounds__(256) void k_max(const unsigned short* __restrict__ znbf,
                                             const unsigned short* __restrict__ ebf,
                                             float* __restrict__ pmaxT) {
    __shared__ float4 lbs5[CHUNK * 5];            // 20 KiB, 80B rows
    __shared__ float lmax[256];
    int kbase = blockIdx.y * CHUNK;
    stage_chunk(ebf, kbase, lbs5, threadIdx.x);
    __syncthreads();

    int wave = threadIdx.x >> 6, lane = threadIdx.x & 63;
    int col = lane & 15, quad = lane >> 4;
    int wtok = blockIdx.x * 256 + wave * 64;

    bf16x8 a[4];                                  // 4 frags = 64 tokens
#pragma unroll
    for (int f = 0; f < 4; ++f)
        a[f] = *(const bf16x8*)(znbf + (size_t)(wtok + f * 16 + col) * CDIM + quad * 8);

    const bf16x8* bl = (const bf16x8*)lbs5;       // 16B units, row stride 5
    const f32x4 zero4 = {0.f, 0.f, 0.f, 0.f};
    float m[4][4];
#pragma unroll
    for (int f = 0; f < 4; ++f)
#pragma unroll
        for (int r = 0; r < 4; ++r) m[f][r] = -1e30f;

    for (int t = 0; t < TILES; ++t) {
        bf16x8 b = bl[(t * 16 + col) * 5 + quad];
#pragma unroll
        for (int f = 0; f < 4; ++f) {
            f32x4 d = __builtin_amdgcn_mfma_f32_16x16x32_bf16(a[f], b, zero4, 0, 0, 0);
#pragma unroll
            for (int r = 0; r < 4; ++r) m[f][r] = fmaxf(m[f][r], d[r]);
        }
    }
#pragma unroll
    for (int f = 0; f < 4; ++f)
#pragma unroll
        for (int r = 0; r < 4; ++r) {
            float v = m[f][r];
#pragma unroll
            for (int s = 1; s < 16; s <<= 1) v = fmaxf(v, __shfl_xor(v, s));
            if (col == 0) lmax[wave * 64 + f * 16 + quad * 4 + r] = v;
        }
    __syncthreads();
    // transposed store: token-major so k_rescan reads 32 maxima as one line.
    pmaxT[(size_t)(blockIdx.x * 256 + threadIdx.x) * NCHUNK + blockIdx.y] =
        lmax[threadIdx.x];
}

// -------- Kernel C: per-token sparse fp32 rescan (coalesced, c-major) ----------
// One wave per token (grid = NTOK/4 blocks of 4 waves). ~1.05 chunks pass per
// token; each passing chunk fp32-rescored from embT: per c, lanes load
// embT[c][ch*256+4*lane] float4 -> 1KB contiguous per instruction.
__global__ __launch_bounds__(256) void k_rescan(const float* __restrict__ zn,
                                                const float* __restrict__ embT,
                                                const float* __restrict__ pmaxT,
                                                unsigned long long* __restrict__ packed) {
    int wave = threadIdx.x >> 6, lane = threadIdx.x & 63;
    int n = blockIdx.x * 4 + wave;

    // 32 chunk maxima: one 128B line
    float pm = -1e30f;
    if (lane < 32) pm = pmaxT[(size_t)n * NCHUNK + lane];
    float mx = pm;
#pragma unroll
    for (int s = 1; s < 64; s <<= 1) mx = fmaxf(mx, __shfl_xor(mx, s));
    float thr = mx - EPSF;
    unsigned m32 = (unsigned)(__ballot(pm >= thr) & 0xFFFFFFFFull);

    // token row (broadcast same-address loads across the wave)
    float zr[CDIM];
    const float4* zp4 = (const float4*)(zn + (size_t)n * CDIM);
#pragma unroll
    for (int j = 0; j < 8; ++j) {
        float4 v4 = zp4[j];
        zr[4 * j + 0] = v4.x;
        zr[4 * j + 1] = v4.y;
        zr[4 * j + 2] = v4.z;
        zr[4 * j + 3] = v4.w;
    }

    unsigned long long kbest = 0ull;
    while (m32) {
        int ch = __ffs(m32) - 1;
        m32 &= m32 - 1;
        const float* bp = embT + ch * CHUNK + 4 * lane;   // lane's 4 codes
        float acc[4][4] = {};                     // acc[c&3][j] - dot32 grouping
#pragma unroll
        for (int c = 0; c < CDIM; ++c) {
            float4 e4 = *(const float4*)(bp + (size_t)c * NCODE);
            int r = c & 3;
            acc[r][0] = __builtin_fmaf(zr[c], e4.x, acc[r][0]);
            acc[r][1] = __builtin_fmaf(zr[c], e4.y, acc[r][1]);
            acc[r][2] = __builtin_fmaf(zr[c], e4.z, acc[r][2]);
            acc[r][3] = __builtin_fmaf(zr[c], e4.w, acc[r][3]);
        }
#pragma unroll
        for (int j = 0; j < 4; ++j) {
            float s = (acc[0][j] + acc[1][j]) + (acc[2][j] + acc[3][j]);
            int code = ch * CHUNK + 4 * lane + j;
            unsigned long long key = ((unsigned long long)fmap(s) << 13) |
                                     (unsigned long long)(8191 - code);
            kbest = kbest > key ? kbest : key;
        }
    }
#pragma unroll
    for (int s = 1; s < 64; s <<= 1) {
        unsigned long long o = __shfl_xor(kbest, s);
        kbest = kbest > o ? kbest : o;
    }
    if (lane == 0) packed[n] = kbest;             // one wave per token: plain store
}

// -------- Kernel D: fused epilogue, 256 blocks (R17-identical) -----------------
// Block b: (a) ids/z_q/loss for tokens 32b..32b+31; (b) bins+esum for codes
// 32b..32b+31 by scanning all packed (coalesced, ~8 hits/wave), then EMA.
__global__ __launch_bounds__(256) void k_final(const unsigned long long* __restrict__ packed,
                                               const float* __restrict__ zn,
                                               const float* __restrict__ emb,
                                               const float* __restrict__ cs,
                                               float* __restrict__ out) {
    __shared__ float lesum[32][32];               // 4 KiB
    __shared__ int lbins[32];
    __shared__ int lsid[32];
    __shared__ float ls4[4];

    int blk = blockIdx.x, t = threadIdx.x;
    int wave = t >> 6, lane = t & 63;
    int tok0 = blk * 32, kbase = blk * 32;

    if (t < 32) lbins[t] = 0;
#pragma unroll
    for (int i = 0; i < 4; ++i) {
        int idx = i * 256 + t;
        lesum[idx >> 5][idx & 31] = 0.f;
    }
    if (t < 32) {                                 // unpack ids for our tokens
        int n = tok0 + t;
        int id = 8191 - (int)(packed[n] & 8191ull);
        lsid[t] = id;
        out[OUT_IDS + n] = (float)id;
    }
    __syncthreads();

    // ---- z_q gather + transpose-out + loss partial ----
    float s = 0.f;
#pragma unroll
    for (int i = 0; i < 4; ++i) {
        int idx = i * 256 + t;
        int tl = idx >> 5, c = idx & 31;
        int n = tok0 + tl;
        int id = lsid[tl];
        float ev = emb[(size_t)id * CDIM + c];    // <=32 rows, L1/L2
        float zv = zn[(size_t)n * CDIM + c];      // coalesced row reads
        int b = n >> 8, hw = n & 255;
        out[OUT_ZQ + ((size_t)b * CDIM + c) * HW + hw] = ev;
        float dd = ev - zv;
        s += dd * dd;
    }
#pragma unroll
    for (int off = 32; off > 0; off >>= 1) s += __shfl_down(s, off);
    if (lane == 0) ls4[wave] = s;
    __syncthreads();
    if (t == 0)
        atomicAdd(out + OUT_LOSS,
                  (ls4[0] + ls4[1] + ls4[2] + ls4[3]) * (1.0f / 262144.0f));

    // ---- bins + esum: scan all tokens for hits in our code window ----
    for (int i = 0; i < 32; ++i) {
        int n = i * 256 + t;                      // coalesced
        int id = 8191 - (int)(packed[n] & 8191ull);
        unsigned kl = (unsigned)(id - kbase);
        if (kl < 32u) {                           // ~8 hits per wave total
            atomicAdd(&lbins[kl], 1);
            const float* zp = zn + (size_t)n * CDIM;
#pragma unroll
            for (int c = 0; c < CDIM; ++c)
                atomicAdd(&lesum[kl][c], zp[c]);
        }
    }
    __syncthreads();

    // ---- EMA update + renormalize for our 32 codes ----
#pragma unroll
    for (int i = 0; i < 4; ++i) {
        int idx = i * 256 + t;
        int kl = idx >> 5, c = idx & 31;
        int k = kbase + kl;
        int bi = lbins[kl];
        float bf = (float)bi;
        bool zero = (bi == 0);
        float tv = lesum[kl][c] / (zero ? 1.0f : bf);
        float ss = tv * tv;
#pragma unroll
        for (int sh = 1; sh < 32; sh <<= 1) ss += __shfl_xor(ss, sh);
        float d = fmaxf(sqrtf(ss), 1e-12f);
        float ew = emb[(size_t)k * CDIM + c];
        float en = zero ? ew : (tv / d);
        float w = ew * DECAYF + (1.0f - DECAYF) * en;
        float ss2 = w * w;
#pragma unroll
        for (int sh = 1; sh < 32; sh <<= 1) ss2 += __shfl_xor(ss2, sh);
        float d2 = fmaxf(sqrtf(ss2), 1e-12f);
        out[OUT_EMB + (size_t)k * CDIM + c] = w / d2;
        if (c == 0) out[OUT_CS + k] = cs[k] * DECAYF + (1.0f - DECAYF) * bf;
    }
}

extern "C" void kernel_launch(void* const* d_in, const int* in_sizes, int n_in,
                              void* d_out, int out_size, void* d_ws, size_t ws_size,
                              hipStream_t stream) {
    const float* z   = (const float*)d_in[0];   // [32,32,16,16]
    const float* emb = (const float*)d_in[1];   // [8192,32]
    const float* cs  = (const float*)d_in[2];   // [8192]
    float* out = (float*)d_out;
    char* ws = (char*)d_ws;

    float* zn                  = (float*)(ws + WS_ZN);
    unsigned short* znbf       = (unsigned short*)(ws + WS_ZNBF);
    unsigned short* ebf        = (unsigned short*)(ws + WS_EBF);
    float* pmaxT               = (float*)(ws + WS_PMAX);
    unsigned long long* packed = (unsigned long long*)(ws + WS_PACK);
    float* embT                = (float*)(ws + WS_EMBT);

    k_prep<<<dim3(161), 256, 0, stream>>>(z, emb, zn, znbf, ebf, embT, out);
    k_max<<<dim3(NTOK / 256, NCHUNK), 256, 0, stream>>>(znbf, ebf, pmaxT);
    k_rescan<<<dim3(NTOK / 4), 256, 0, stream>>>(zn, embT, pmaxT, packed);
    k_final<<<dim3(256), 256, 0, stream>>>(packed, zn, emb, cs, out);
}